// Round 1
// baseline (438.637 us; speedup 1.0000x reference)
//
#include <hip/hip_runtime.h>
#include <hip/hip_bf16.h>

// Problem constants
#define B_ 4
#define S_ 2048
#define D_ 128
#define H_ 8

typedef __attribute__((ext_vector_type(8))) short bf16x8;
typedef __attribute__((ext_vector_type(4))) float f32x4;

__device__ __forceinline__ short f2bf(float f) {
  union { float f; unsigned u; } v; v.f = f;
  unsigned u = v.u;
  unsigned r = (u + 0x7FFFu + ((u >> 16) & 1u)) >> 16;
  return (short)r;
}

// fp32 -> bf16 elementwise convert (vectorized x4)
__global__ void cvt_bf16(const float* __restrict__ in, short* __restrict__ out, int n4) {
  int i = blockIdx.x * blockDim.x + threadIdx.x;
  if (i >= n4) return;
  float4 v = ((const float4*)in)[i];
  short4 o = make_short4(f2bf(v.x), f2bf(v.y), f2bf(v.z), f2bf(v.w));
  ((short4*)out)[i] = o;
}

// W (128,1024) fp32 -> Wt (1024,128) bf16 (Wt[n][k] = W[k][n])
__global__ void transpose_w(const float* __restrict__ W, short* __restrict__ Wt) {
  int t = blockIdx.x * blockDim.x + threadIdx.x; // 131072 total
  int n = t >> 7, k = t & 127;
  Wt[t] = f2bf(W[k * 1024 + n]);
}

// GEMM: out[b,h,s,d] = xb(8192,128) @ Wt^T + bias ; per-wave 16x64 tile, K=128
__global__ __launch_bounds__(256) void proj_qk(const short* __restrict__ xb,
                                               const short* __restrict__ Wt,
                                               const float* __restrict__ bias,
                                               short* __restrict__ out) {
  int lane = threadIdx.x & 63, w = threadIdx.x >> 6;
  int task = blockIdx.x * 4 + w;       // 8192 tasks
  int mt = task >> 4, nst = task & 15; // 512 m-tiles x 16 n-strips(64)
  int l15 = lane & 15, l4 = lane >> 4;
  int koff = l4 * 8;
  int m = mt * 16 + l15;
  bf16x8 a[4];
#pragma unroll
  for (int st = 0; st < 4; ++st)
    a[st] = *(const bf16x8*)(xb + m * 128 + koff + 32 * st);
#pragma unroll
  for (int nt = 0; nt < 4; ++nt) {
    int n = nst * 64 + nt * 16 + l15;
    f32x4 acc = {0.f, 0.f, 0.f, 0.f};
#pragma unroll
    for (int st = 0; st < 4; ++st) {
      bf16x8 b = *(const bf16x8*)(Wt + n * 128 + koff + 32 * st);
      acc = __builtin_amdgcn_mfma_f32_16x16x32_bf16(a[st], b, acc, 0, 0, 0);
    }
    float bv = bias[n];
    int h = n >> 7, d = n & 127;
#pragma unroll
    for (int r = 0; r < 4; ++r) {
      int mrow = mt * 16 + l4 * 4 + r;
      int bb = mrow >> 11, s = mrow & 2047;
      out[(((bb * H_ + h) * S_ + s) * D_) + d] = f2bf(acc[r] + bv);
    }
  }
}

// Transposed GEMM for V: C' = Wt(1024,128) x xb^T -> Vt[b,h,d,s] (stores contiguous in s)
__global__ __launch_bounds__(256) void proj_v(const short* __restrict__ xb,
                                              const short* __restrict__ Wt,
                                              const float* __restrict__ bias,
                                              short* __restrict__ out) {
  int lane = threadIdx.x & 63, w = threadIdx.x >> 6;
  int task = blockIdx.x * 4 + w;         // 8192 tasks
  int hdT = task >> 7, nst = task & 127; // 64 hd-tiles x 128 s-strips(64)
  int l15 = lane & 15, l4 = lane >> 4;
  int koff = l4 * 8;
  int hda = hdT * 16 + l15;
  bf16x8 a[4];
#pragma unroll
  for (int st = 0; st < 4; ++st)
    a[st] = *(const bf16x8*)(Wt + hda * 128 + koff + 32 * st);
#pragma unroll
  for (int nt = 0; nt < 4; ++nt) {
    int scol = nst * 64 + nt * 16 + l15; // global (b*s) index
    f32x4 acc = {0.f, 0.f, 0.f, 0.f};
#pragma unroll
    for (int st = 0; st < 4; ++st) {
      bf16x8 b = *(const bf16x8*)(xb + scol * 128 + koff + 32 * st);
      acc = __builtin_amdgcn_mfma_f32_16x16x32_bf16(a[st], b, acc, 0, 0, 0);
    }
    int bb = scol >> 11, s = scol & 2047;
#pragma unroll
    for (int r = 0; r < 4; ++r) {
      int hd = hdT * 16 + l4 * 4 + r;
      int h = hd >> 7, d = hd & 127;
      out[((bb * H_ + h) * D_ + d) * S_ + s] = f2bf(acc[r] + bias[hd]);
    }
  }
}

// Flash-style attention with |score| softmax.
// Block: (b,h,q-tile of 64). 4 waves x 16 q-rows. BN=64 keys/iter.
#define BN 64
#define KSTR 136 // 128 + 8 pad (bf16 elems)
#define VSTR 72  // 64 + 8 pad
#define PSTR 72

__global__ __launch_bounds__(256) void attn(const short* __restrict__ Qp,
                                            const short* __restrict__ Kp,
                                            const short* __restrict__ Vt,
                                            float* __restrict__ out) {
  __shared__ short sK[64 * KSTR];
  __shared__ short sV[128 * VSTR];
  __shared__ short sP[4 * 16 * PSTR];

  int lane = threadIdx.x & 63, w = threadIdx.x >> 6;
  int qt = blockIdx.x & 31; // 32 q-tiles
  int bh = blockIdx.x >> 5; // 0..31
  int q0 = qt * 64;
  int l15 = lane & 15, l4 = lane >> 4;
  int koff = l4 * 8;

  const short* Qbase = Qp + (size_t)bh * S_ * D_;
  const short* Kbase = Kp + (size_t)bh * S_ * D_;
  const short* Vbase = Vt + (size_t)bh * D_ * S_;

  // Preload Q A-fragments (16 rows x 128 k per wave)
  bf16x8 aq[4];
  int qrow = q0 + w * 16 + l15;
#pragma unroll
  for (int st = 0; st < 4; ++st)
    aq[st] = *(const bf16x8*)(Qbase + qrow * D_ + koff + 32 * st);

  float m_run[4], l_run[4];
  f32x4 oacc[8];
#pragma unroll
  for (int r = 0; r < 4; ++r) { m_run[r] = -1e30f; l_run[r] = 0.f; }
#pragma unroll
  for (int t = 0; t < 8; ++t) oacc[t] = (f32x4){0.f, 0.f, 0.f, 0.f};

  const float SC2 = 0.127530637f; // log2(e)/sqrt(128)

  for (int kt = 0; kt < S_; kt += BN) {
    __syncthreads(); // protect LDS tiles from previous iteration's readers
    // Stage K tile: 64 rows x 128 cols bf16, 1024 chunks of 8
#pragma unroll
    for (int i = 0; i < 4; ++i) {
      int c = threadIdx.x + 256 * i;
      int row = c >> 4, c8 = c & 15;
      *(bf16x8*)(sK + row * KSTR + c8 * 8) =
          *(const bf16x8*)(Kbase + (kt + row) * D_ + c8 * 8);
    }
    // Stage V tile (transposed layout): 128 d-rows x 64 s-cols
#pragma unroll
    for (int i = 0; i < 4; ++i) {
      int c = threadIdx.x + 256 * i;
      int dd = c >> 3, c8 = c & 7;
      *(bf16x8*)(sV + dd * VSTR + c8 * 8) =
          *(const bf16x8*)(Vbase + dd * S_ + kt + c8 * 8);
    }
    __syncthreads();

    // S = Q K^T  (per wave: 16 x 64)
    f32x4 sc[4];
#pragma unroll
    for (int nt = 0; nt < 4; ++nt) {
      f32x4 acc = {0.f, 0.f, 0.f, 0.f};
#pragma unroll
      for (int st = 0; st < 4; ++st) {
        bf16x8 bk = *(const bf16x8*)(sK + (nt * 16 + l15) * KSTR + koff + 32 * st);
        acc = __builtin_amdgcn_mfma_f32_16x16x32_bf16(aq[st], bk, acc, 0, 0, 0);
      }
      sc[nt] = acc;
    }

    // abs + scale into exp2 domain; per-row tile max
    float mt_[4];
#pragma unroll
    for (int r = 0; r < 4; ++r) {
      sc[0][r] = fabsf(sc[0][r]) * SC2;
      sc[1][r] = fabsf(sc[1][r]) * SC2;
      sc[2][r] = fabsf(sc[2][r]) * SC2;
      sc[3][r] = fabsf(sc[3][r]) * SC2;
      mt_[r] = fmaxf(fmaxf(sc[0][r], sc[1][r]), fmaxf(sc[2][r], sc[3][r]));
    }
#pragma unroll
    for (int mask = 1; mask < 16; mask <<= 1) {
#pragma unroll
      for (int r = 0; r < 4; ++r)
        mt_[r] = fmaxf(mt_[r], __shfl_xor(mt_[r], mask));
    }
    float alpha[4];
#pragma unroll
    for (int r = 0; r < 4; ++r) {
      float mn = fmaxf(m_run[r], mt_[r]);
      alpha[r] = __builtin_amdgcn_exp2f(m_run[r] - mn);
      m_run[r] = mn;
    }
    // P = exp2(s - m), write to per-wave LDS region (C-layout -> row-major)
    float ls[4] = {0.f, 0.f, 0.f, 0.f};
    short* pw = sP + w * 16 * PSTR;
#pragma unroll
    for (int nt = 0; nt < 4; ++nt) {
#pragma unroll
      for (int r = 0; r < 4; ++r) {
        float p = __builtin_amdgcn_exp2f(sc[nt][r] - m_run[r]);
        ls[r] += p;
        pw[(l4 * 4 + r) * PSTR + nt * 16 + l15] = f2bf(p);
      }
    }
#pragma unroll
    for (int mask = 1; mask < 16; mask <<= 1) {
#pragma unroll
      for (int r = 0; r < 4; ++r) ls[r] += __shfl_xor(ls[r], mask);
    }
#pragma unroll
    for (int r = 0; r < 4; ++r) l_run[r] = l_run[r] * alpha[r] + ls[r];
    // rescale O accumulator
#pragma unroll
    for (int t = 0; t < 8; ++t) {
#pragma unroll
      for (int r = 0; r < 4; ++r) oacc[t][r] *= alpha[r];
    }
    // O += P V  (A-frags of P from LDS; B-frags of V from LDS)
    bf16x8 ap[2];
#pragma unroll
    for (int kst = 0; kst < 2; ++kst)
      ap[kst] = *(const bf16x8*)(pw + l15 * PSTR + koff + 32 * kst);
#pragma unroll
    for (int t = 0; t < 8; ++t) {
#pragma unroll
      for (int kst = 0; kst < 2; ++kst) {
        bf16x8 bv = *(const bf16x8*)(sV + (t * 16 + l15) * VSTR + koff + 32 * kst);
        oacc[t] = __builtin_amdgcn_mfma_f32_16x16x32_bf16(ap[kst], bv, oacc[t], 0, 0, 0);
      }
    }
  }

  // epilogue: out[b, q, h*128 + dv] fp32
  int bb = bh >> 3, h = bh & 7;
#pragma unroll
  for (int t = 0; t < 8; ++t) {
#pragma unroll
    for (int r = 0; r < 4; ++r) {
      int row = l4 * 4 + r;
      int q = q0 + w * 16 + row;
      out[((size_t)(bb * S_ + q)) * (H_ * D_) + h * D_ + t * 16 + l15] =
          oacc[t][r] / l_run[r];
    }
  }
}

extern "C" void kernel_launch(void* const* d_in, const int* in_sizes, int n_in,
                              void* d_out, int out_size, void* d_ws, size_t ws_size,
                              hipStream_t stream) {
  (void)in_sizes; (void)n_in; (void)out_size; (void)ws_size;
  const float* q  = (const float*)d_in[0];
  const float* k  = (const float*)d_in[1];
  const float* v  = (const float*)d_in[2];
  const float* WQ = (const float*)d_in[3];
  const float* bQ = (const float*)d_in[4];
  const float* WK = (const float*)d_in[5];
  const float* bK = (const float*)d_in[6];
  const float* WV = (const float*)d_in[7];
  const float* bV = (const float*)d_in[8];

  const int NX = B_ * S_ * D_;      // 1048576 elems per input tensor
  const int NW = D_ * H_ * D_;      // 131072 per weight
  const int NP = B_ * H_ * S_ * D_; // 8388608 per projected tensor

  short* ws  = (short*)d_ws;
  short* xq  = ws;
  short* xk  = xq + NX;
  short* xv  = xk + NX;
  short* wtq = xv + NX;
  short* wtk = wtq + NW;
  short* wtv = wtk + NW;
  short* Qp  = wtv + NW;
  short* Kp  = Qp + NP;
  short* Vt  = Kp + NP;

  cvt_bf16<<<NX / 4 / 256, 256, 0, stream>>>(q, xq, NX / 4);
  cvt_bf16<<<NX / 4 / 256, 256, 0, stream>>>(k, xk, NX / 4);
  cvt_bf16<<<NX / 4 / 256, 256, 0, stream>>>(v, xv, NX / 4);
  transpose_w<<<NW / 256, 256, 0, stream>>>(WQ, wtq);
  transpose_w<<<NW / 256, 256, 0, stream>>>(WK, wtk);
  transpose_w<<<NW / 256, 256, 0, stream>>>(WV, wtv);

  proj_qk<<<2048, 256, 0, stream>>>(xq, wtq, bQ, Qp);
  proj_qk<<<2048, 256, 0, stream>>>(xk, wtk, bK, Kp);
  proj_v<<<2048, 256, 0, stream>>>(xv, wtv, bV, Vt);

  attn<<<1024, 256, 0, stream>>>(Qp, Kp, Vt, (float*)d_out);
}